// Round 4
// baseline (18797.675 us; speedup 1.0000x reference)
//
#include <hip/hip_runtime.h>
#include <math.h>

// Problem constants
#define Bb    64
#define Ss    1024
#define CINc  256
#define Hh    512
#define Kk    768          // CIN + H
#define NBLK  256          // one block per CU; each owns 2 hidden units (8 gate rows)
#define NTHR  512          // 8 waves; EACH wave: all 8 slots, 1/8 of k (16-k slices)
#define SLOTS 8            // 4 gates x 2 units

// ws layout: [wt2: NBLK*Kk*SLOTS f32][hbuf: 2*B*H f32][ctr: 8 x 64B]
#define WT_FLOATS   (NBLK * SLOTS * Kk)
#define HBUF_FLOATS (2 * Bb * Hh)
#define NCTR 8
#define CTR_STRIDE 16      // uints -> 64 B apart (separate cache lines)

// Extract center-tap weights into block-major, k-major, slot-minor layout:
// wt2[bl][k][s] = W[(col*Kk + k)*3 + 1], col = 2*bl + (s&1) + Hh*(s>>1)
__global__ void extract_weights(const float* __restrict__ W, float* __restrict__ wt) {
    int total = WT_FLOATS;
    for (int idx = blockIdx.x * blockDim.x + threadIdx.x; idx < total;
         idx += gridDim.x * blockDim.x) {
        int s    = idx & 7;
        int rest = idx >> 3;
        int k    = rest % Kk;
        int bl   = rest / Kk;
        int col  = 2 * bl + (s & 1) + Hh * (s >> 1);
        wt[idx] = W[((size_t)col * Kk + k) * 3 + 1];
    }
}

__device__ __forceinline__ float sigf(float v) { return 1.0f / (1.0f + expf(-v)); }

// Explicit vmcnt control. All in-loop VMEM is inline-asm so the counts are ours.
__device__ __forceinline__ void wait_vm0() {
    asm volatile("s_waitcnt vmcnt(0)" ::: "memory");
}
__device__ __forceinline__ void wait_vm8() {
    asm volatile("s_waitcnt vmcnt(8)" ::: "memory");
    __builtin_amdgcn_sched_barrier(0);   // rule #18: keep reg-only FMAs below the wait
}
// LLC-coherent (bypass L1+L2) load/store for the h exchange.
__device__ __forceinline__ float4 load4_llc(const float* p) {
    float4 v;
    asm volatile("global_load_dwordx4 %0, %1, off sc0 sc1" : "=&v"(v) : "v"(p) : "memory");
    return v;
}
// Ordinary cached load, but asm-issued so it doesn't perturb our vmcnt counting.
__device__ __forceinline__ float4 load4_glb(const float* p) {
    float4 v;
    asm volatile("global_load_dwordx4 %0, %1, off" : "=&v"(v) : "v"(p) : "memory");
    return v;
}
__device__ __forceinline__ void store_llc(float* p, float v) {
    asm volatile("global_store_dword %0, %1, off sc0 sc1" :: "v"(p), "v"(v) : "memory");
}

// 4 consecutive k (one float4 of activations) x 8 slots = 32 FMAs, 8 LDS b128 reads.
// wp = w row for first k (stride SLOTS floats per k).
__device__ __forceinline__ void fma4(const float* wp, float4 av, float* acc) {
    const float4* w4 = (const float4*)wp;
    float4 a0 = w4[0], b0 = w4[1];
    float4 a1 = w4[2], b1 = w4[3];
    float4 a2 = w4[4], b2 = w4[5];
    float4 a3 = w4[6], b3 = w4[7];
    acc[0] = fmaf(av.x, a0.x, acc[0]); acc[1] = fmaf(av.x, a0.y, acc[1]);
    acc[2] = fmaf(av.x, a0.z, acc[2]); acc[3] = fmaf(av.x, a0.w, acc[3]);
    acc[4] = fmaf(av.x, b0.x, acc[4]); acc[5] = fmaf(av.x, b0.y, acc[5]);
    acc[6] = fmaf(av.x, b0.z, acc[6]); acc[7] = fmaf(av.x, b0.w, acc[7]);
    acc[0] = fmaf(av.y, a1.x, acc[0]); acc[1] = fmaf(av.y, a1.y, acc[1]);
    acc[2] = fmaf(av.y, a1.z, acc[2]); acc[3] = fmaf(av.y, a1.w, acc[3]);
    acc[4] = fmaf(av.y, b1.x, acc[4]); acc[5] = fmaf(av.y, b1.y, acc[5]);
    acc[6] = fmaf(av.y, b1.z, acc[6]); acc[7] = fmaf(av.y, b1.w, acc[7]);
    acc[0] = fmaf(av.z, a2.x, acc[0]); acc[1] = fmaf(av.z, a2.y, acc[1]);
    acc[2] = fmaf(av.z, a2.z, acc[2]); acc[3] = fmaf(av.z, a2.w, acc[3]);
    acc[4] = fmaf(av.z, b2.x, acc[4]); acc[5] = fmaf(av.z, b2.y, acc[5]);
    acc[6] = fmaf(av.z, b2.z, acc[6]); acc[7] = fmaf(av.z, b2.w, acc[7]);
    acc[0] = fmaf(av.w, a3.x, acc[0]); acc[1] = fmaf(av.w, a3.y, acc[1]);
    acc[2] = fmaf(av.w, a3.z, acc[2]); acc[3] = fmaf(av.w, a3.w, acc[3]);
    acc[4] = fmaf(av.w, b3.x, acc[4]); acc[5] = fmaf(av.w, b3.y, acc[5]);
    acc[6] = fmaf(av.w, b3.z, acc[6]); acc[7] = fmaf(av.w, b3.w, acc[7]);
}

__global__ __launch_bounds__(NTHR, 1) void lstm_coop(
    const float* __restrict__ x,    // [B,S,CIN]
    const float* __restrict__ bias, // [4H]
    const float* __restrict__ h0,   // [B,H]
    const float* __restrict__ c0,   // [B,H]
    const float* __restrict__ wt,   // [NBLK][Kk][SLOTS]
    float* __restrict__ hbuf,       // [2][B][H]  (LLC-coherent access only)
    unsigned* ctr,                  // 8 striped barrier counters
    float* __restrict__ out)        // [B,S,H] ++ [B,H] ++ [B,H]
{
    __shared__ float w_lds[Kk * SLOTS];          // 24 KB, [k][s]
    __shared__ float g_par[SLOTS][SLOTS][Bb];    // 16 KB, [wave][slot][b]

    const int tid  = threadIdx.x;
    const int lane = tid & 63;
    const int q    = __builtin_amdgcn_readfirstlane(tid >> 6);  // wave 0..7
    const int bl   = blockIdx.x;
    const int u0   = 2 * bl;

    // ---- stage this block's weights into LDS once ----
    {
        const float4* wsrc = (const float4*)(wt + (size_t)bl * SLOTS * Kk);
        float4* wdst = (float4*)w_lds;
        for (int i = tid; i < SLOTS * Kk / 4; i += NTHR) wdst[i] = wsrc[i];
    }
    // wave q owns k-slices [16q,16q+16) of each 128-chunk; base ptr folds the 16q.
    const float* wq = w_lds + 16 * q * SLOTS;

    // ---- init hbuf[0] = h0 with LLC-coherent stores ----
    for (int i = bl * NTHR + tid; i < Bb * Hh; i += NBLK * NTHR) store_llc(&hbuf[i], h0[i]);
    wait_vm0();

    float cstate = 0.f;
    int   ucell  = 0;
    float bi = 0.f, bf = 0.f, bg = 0.f, bo = 0.f;
    if (q < 2) {
        ucell  = u0 + q;
        cstate = c0[(size_t)lane * Hh + ucell];
        bi = bias[ucell];
        bf = bias[ucell + Hh];
        bg = bias[ucell + 2 * Hh];
        bo = bias[ucell + 3 * Hh];
    }

    __syncthreads();
    // ---- barrier phase 1 arrival ----
    if (tid == 0) __hip_atomic_fetch_add(&ctr[(bl & 7) * CTR_STRIDE], 1u,
                                         __ATOMIC_RELAXED, __HIP_MEMORY_SCOPE_AGENT);

    // ---- x-part prologue for t=0 (hidden under barrier settle) ----
    const float* xb = x + (size_t)lane * Ss * CINc + 16 * q;  // batch = lane
    float4 xv[8];
    float  accx[SLOTS];
    {
        #pragma unroll
        for (int c = 0; c < 2; ++c)
            #pragma unroll
            for (int f = 0; f < 4; ++f)
                xv[c * 4 + f] = load4_glb(xb + 128 * c + 4 * f);   // t=0
        wait_vm0();
        #pragma unroll
        for (int s = 0; s < SLOTS; ++s) accx[s] = 0.f;
        #pragma unroll
        for (int c = 0; c < 2; ++c)
            #pragma unroll
            for (int f = 0; f < 4; ++f)
                fma4(wq + (128 * c + 4 * f) * SLOTS, xv[c * 4 + f], accx);
    }

    if (tid < NCTR) {
        while (__hip_atomic_load(&ctr[tid * CTR_STRIDE],
                                 __ATOMIC_RELAXED, __HIP_MEMORY_SCOPE_AGENT) < 32u)
            __builtin_amdgcn_s_sleep(2);
    }
    __atomic_signal_fence(__ATOMIC_SEQ_CST);
    __syncthreads();

    for (int t = 0; t < Ss; ++t) {
        const int cur = t & 1;
        const float* hcur = hbuf + (size_t)cur * Bb * Hh;
        float*       hnxt = hbuf + (size_t)(cur ^ 1) * Bb * Hh;

        // ---- issue all 16 h loads (LLC) for this step ----
        const float* hb = hcur + (size_t)lane * Hh + 16 * q;
        float4 hv[16];
        #pragma unroll
        for (int c = 0; c < 4; ++c)
            #pragma unroll
            for (int f = 0; f < 4; ++f)
                hv[c * 4 + f] = load4_llc(hb + 128 * c + 4 * f);

        float acc[SLOTS];
        #pragma unroll
        for (int s = 0; s < SLOTS; ++s) acc[s] = accx[s];

        wait_vm8();   // hv[0..7] landed (in-order retirement)
        #pragma unroll
        for (int c = 0; c < 2; ++c)
            #pragma unroll
            for (int f = 0; f < 4; ++f)
                fma4(wq + (256 + 128 * c + 4 * f) * SLOTS, hv[c * 4 + f], acc);

        wait_vm0();   // hv[8..15] landed; vmcnt now 0 -> clean slate for x issue
        __builtin_amdgcn_sched_barrier(0);

        // ---- issue next step's x loads (cached); latency hidden under the tail ----
        {
            const int tn = (t + 1) & (Ss - 1);   // t=Ss-1 wraps to 0 (result unused)
            const float* xbt = xb + (size_t)tn * CINc;
            #pragma unroll
            for (int c = 0; c < 2; ++c)
                #pragma unroll
                for (int f = 0; f < 4; ++f)
                    xv[c * 4 + f] = load4_glb(xbt + 128 * c + 4 * f);
        }

        #pragma unroll
        for (int c = 2; c < 4; ++c)
            #pragma unroll
            for (int f = 0; f < 4; ++f)
                fma4(wq + (256 + 128 * c + 4 * f) * SLOTS, hv[c * 4 + f], acc);

        // ---- gate reduction ----
        #pragma unroll
        for (int s = 0; s < SLOTS; ++s) g_par[q][s][lane] = acc[s];
        asm volatile("s_waitcnt lgkmcnt(0)" ::: "memory");
        __builtin_amdgcn_sched_barrier(0);
        __builtin_amdgcn_s_barrier();
        asm volatile("" ::: "memory");

        if (q < 2) {   // waves 0,1: cell update for units u0+q, b = lane
            float s0 = 0.f, s1 = 0.f, s2 = 0.f, s3 = 0.f;
            #pragma unroll
            for (int w = 0; w < SLOTS; ++w) {
                s0 += g_par[w][0 + q][lane];   // gate i
                s1 += g_par[w][2 + q][lane];   // gate f
                s2 += g_par[w][4 + q][lane];   // gate g
                s3 += g_par[w][6 + q][lane];   // gate o
            }
            float iv = sigf(s0 + bi);
            float fv = sigf(s1 + bf);
            float gv = tanhf(s2 + bg);
            float ov = sigf(s3 + bo);
            cstate = fv * cstate + iv * gv;
            float hv_ = ov * tanhf(cstate);
            store_llc(&hnxt[(size_t)lane * Hh + ucell], hv_);   // coherent publish
            out[((size_t)lane * Ss + t) * Hh + ucell] = hv_;
            if (t == Ss - 1) {
                out[(size_t)Bb * Ss * Hh + (size_t)lane * Hh + ucell] = hv_;
                out[(size_t)Bb * Ss * Hh + (size_t)Bb * Hh + (size_t)lane * Hh + ucell] = cstate;
            }
        }
        wait_vm0();        // drain h store (critical) + out stores + x prefetch (done)
        __builtin_amdgcn_s_barrier();
        asm volatile("" ::: "memory");

        // ---- grid barrier arrival, phase t+2 ----
        if (tid == 0) __hip_atomic_fetch_add(&ctr[(bl & 7) * CTR_STRIDE], 1u,
                                             __ATOMIC_RELAXED, __HIP_MEMORY_SCOPE_AGENT);

        // ---- x-part GEMM for step t+1, hidden under barrier settle ----
        #pragma unroll
        for (int s = 0; s < SLOTS; ++s) accx[s] = 0.f;
        #pragma unroll
        for (int c = 0; c < 2; ++c)
            #pragma unroll
            for (int f = 0; f < 4; ++f)
                fma4(wq + (128 * c + 4 * f) * SLOTS, xv[c * 4 + f], accx);

        const unsigned target = 32u * (unsigned)(t + 2);
        if (tid < NCTR) {
            while (__hip_atomic_load(&ctr[tid * CTR_STRIDE],
                                     __ATOMIC_RELAXED, __HIP_MEMORY_SCOPE_AGENT) < target)
                __builtin_amdgcn_s_sleep(2);
        }
        __atomic_signal_fence(__ATOMIC_SEQ_CST);
        __builtin_amdgcn_s_barrier();
        asm volatile("" ::: "memory");
    }
}

extern "C" void kernel_launch(void* const* d_in, const int* in_sizes, int n_in,
                              void* d_out, int out_size, void* d_ws, size_t ws_size,
                              hipStream_t stream) {
    const float* x    = (const float*)d_in[0];
    const float* W    = (const float*)d_in[1];
    const float* bias = (const float*)d_in[2];
    const float* h0   = (const float*)d_in[3];
    const float* c0   = (const float*)d_in[4];
    float* out = (float*)d_out;

    float*    wt   = (float*)d_ws;
    float*    hbuf = wt + WT_FLOATS;
    unsigned* ctr  = (unsigned*)(hbuf + HBUF_FLOATS);

    hipMemsetAsync(ctr, 0, NCTR * CTR_STRIDE * sizeof(unsigned), stream);
    extract_weights<<<256, 256, 0, stream>>>(W, wt);

    void* args[] = { (void*)&x, (void*)&bias, (void*)&h0, (void*)&c0,
                     (void*)&wt, (void*)&hbuf, (void*)&ctr, (void*)&out };
    hipLaunchCooperativeKernel((const void*)lstm_coop, dim3(NBLK), dim3(NTHR),
                               args, 0, stream);
}

// Round 6
// 12827.640 us; speedup vs baseline: 1.4654x; 1.4654x over previous
//
#include <hip/hip_runtime.h>
#include <math.h>

// Problem constants
#define Bb    64
#define Ss    1024
#define CINc  256
#define Hh    512
#define Kk    768          // CIN + H
#define NBLK  256          // one block per CU; each owns 2 hidden units (8 gate rows)
#define NTHR  512          // 8 waves; thread (bb=tid>>3, sub=tid&7): batch bb, k-slice sub
#define SLOTS 8            // 4 gates x 2 units
#define WSTRIDE 6144       // floats of w per block: 8 per k, granule-XOR swizzled

// ws layout: [wt: NBLK*WSTRIDE f32][hbuf: 2*B*H f32][ctr: 8 x 64B]
#define WT_FLOATS   (NBLK * WSTRIDE)
#define HBUF_FLOATS (2 * Bb * Hh)
#define NCTR 8
#define CTR_STRIDE 16      // uints -> 64 B apart (separate cache lines)

// Extract center-tap weights, granule-swizzled:
// logical element (k, s) of block bl -> granule g=k>>2, float4 f=2*(k&3)+(s>>2),
// stored at bl*WSTRIDE + 32*g + 4*(f ^ (g&7)) + (s&3).
// Reader thread sub only touches granules with g&7==sub -> banks 4*(i^sub): conflict-free.
__global__ void extract_weights(const float* __restrict__ W, float* __restrict__ wt) {
    int total = NBLK * Kk * SLOTS;
    for (int idx = blockIdx.x * blockDim.x + threadIdx.x; idx < total;
         idx += gridDim.x * blockDim.x) {
        int s    = idx & 7;
        int k    = (idx >> 3) % Kk;
        int bl   = idx / (Kk * SLOTS);
        int col  = 2 * bl + (s & 1) + Hh * (s >> 1);
        int g    = k >> 2;
        int f    = ((k & 3) << 1) | (s >> 2);
        int dst  = bl * WSTRIDE + (g << 5) + (((f ^ (g & 7)) << 2) | (s & 3));
        wt[dst] = W[((size_t)col * Kk + k) * 3 + 1];
    }
}

__device__ __forceinline__ float sigf(float v) { return 1.0f / (1.0f + expf(-v)); }

// Explicit vmcnt control; all in-loop VMEM is asm so counts are ours.
// "memory" kept ONLY on waits/stores; loads rely on volatile mutual ordering +
// sched_barrier(0) after waits (rule #18) -> frees the register allocator.
__device__ __forceinline__ void wait_vm0() {
    asm volatile("s_waitcnt vmcnt(0)" ::: "memory");
}
__device__ __forceinline__ void wait_vm8() {
    asm volatile("s_waitcnt vmcnt(8)" ::: "memory");
    __builtin_amdgcn_sched_barrier(0);
}
__device__ __forceinline__ float4 load4_llc(const float* p) {
    float4 v;
    asm volatile("global_load_dwordx4 %0, %1, off sc0 sc1" : "=&v"(v) : "v"(p));
    return v;
}
__device__ __forceinline__ float4 load4_glb(const float* p) {
    float4 v;
    asm volatile("global_load_dwordx4 %0, %1, off" : "=&v"(v) : "v"(p));
    return v;
}
__device__ __forceinline__ void store_llc(float* p, float v) {
    asm volatile("global_store_dword %0, %1, off sc0 sc1" :: "v"(p), "v"(v) : "memory");
}

// One granule (4 k) x 8 slots = 32 FMAs. w comes from 8 pre-XORed float4
// pointers (wq[i] = w_lds4 + (i^sub) + 8*sub); fo = 8*g - 8*sub (compile-time
// per unrolled call). Pair i covers k-offset i: a_i = slots 0-3, b_i = slots 4-7.
__device__ __forceinline__ void gfma(const float4* const* wq, int fo, float4 av, float* acc) {
    float4 a0 = wq[0][fo], b0 = wq[1][fo];
    float4 a1 = wq[2][fo], b1 = wq[3][fo];
    float4 a2 = wq[4][fo], b2 = wq[5][fo];
    float4 a3 = wq[6][fo], b3 = wq[7][fo];
    acc[0] = fmaf(av.x, a0.x, acc[0]); acc[1] = fmaf(av.x, a0.y, acc[1]);
    acc[2] = fmaf(av.x, a0.z, acc[2]); acc[3] = fmaf(av.x, a0.w, acc[3]);
    acc[4] = fmaf(av.x, b0.x, acc[4]); acc[5] = fmaf(av.x, b0.y, acc[5]);
    acc[6] = fmaf(av.x, b0.z, acc[6]); acc[7] = fmaf(av.x, b0.w, acc[7]);
    acc[0] = fmaf(av.y, a1.x, acc[0]); acc[1] = fmaf(av.y, a1.y, acc[1]);
    acc[2] = fmaf(av.y, a1.z, acc[2]); acc[3] = fmaf(av.y, a1.w, acc[3]);
    acc[4] = fmaf(av.y, b1.x, acc[4]); acc[5] = fmaf(av.y, b1.y, acc[5]);
    acc[6] = fmaf(av.y, b1.z, acc[6]); acc[7] = fmaf(av.y, b1.w, acc[7]);
    acc[0] = fmaf(av.z, a2.x, acc[0]); acc[1] = fmaf(av.z, a2.y, acc[1]);
    acc[2] = fmaf(av.z, a2.z, acc[2]); acc[3] = fmaf(av.z, a2.w, acc[3]);
    acc[4] = fmaf(av.z, b2.x, acc[4]); acc[5] = fmaf(av.z, b2.y, acc[5]);
    acc[6] = fmaf(av.z, b2.z, acc[6]); acc[7] = fmaf(av.z, b2.w, acc[7]);
    acc[0] = fmaf(av.w, a3.x, acc[0]); acc[1] = fmaf(av.w, a3.y, acc[1]);
    acc[2] = fmaf(av.w, a3.z, acc[2]); acc[3] = fmaf(av.w, a3.w, acc[3]);
    acc[4] = fmaf(av.w, b3.x, acc[4]); acc[5] = fmaf(av.w, b3.y, acc[5]);
    acc[6] = fmaf(av.w, b3.z, acc[6]); acc[7] = fmaf(av.w, b3.w, acc[7]);
}

__global__ __launch_bounds__(NTHR, 1) void lstm_coop(
    const float* __restrict__ x,    // [B,S,CIN]
    const float* __restrict__ bias, // [4H]
    const float* __restrict__ h0,   // [B,H]
    const float* __restrict__ c0,   // [B,H]
    const float* __restrict__ wt,   // [NBLK][WSTRIDE] swizzled
    float* __restrict__ hbuf,       // [2][B][H]  (LLC-coherent access only)
    unsigned* ctr,                  // 8 striped barrier counters
    float* __restrict__ out)        // [B,S,H] ++ [B,H] ++ [B,H]
{
    __shared__ float w_lds[WSTRIDE];       // 24 KB
    __shared__ float g_par[8 * 516];       // 16.1 KB, [sub][slot*64 + bb], sub-stride 516

    const int tid  = threadIdx.x;
    const int lane = tid & 63;
    const int q    = __builtin_amdgcn_readfirstlane(tid >> 6);  // wave 0..7
    const int bl   = blockIdx.x;
    const int u0   = 2 * bl;
    const int bb   = tid >> 3;     // batch row this thread loads/accumulates
    const int sub  = tid & 7;      // k-slice: granules with g&7 == sub

    // ---- stage this block's weights into LDS once ----
    {
        const float4* wsrc = (const float4*)(wt + (size_t)bl * WSTRIDE);
        float4* wdst = (float4*)w_lds;
        for (int i = tid; i < WSTRIDE / 4; i += NTHR) wdst[i] = wsrc[i];
    }
    // 8 pre-XORed w base pointers; granule fo: x -> 64*j, h -> 512 + 64*j.
    const float4* wqs4[8];
    #pragma unroll
    for (int i = 0; i < 8; ++i)
        wqs4[i] = ((const float4*)w_lds) + (i ^ sub) + 8 * sub;

    // ---- init hbuf[0] = h0 with LLC-coherent stores ----
    for (int i = bl * NTHR + tid; i < Bb * Hh; i += NBLK * NTHR) store_llc(&hbuf[i], h0[i]);
    wait_vm0();

    float cstate = 0.f;
    int   ucell  = 0;
    float bi = 0.f, bf = 0.f, bg = 0.f, bo = 0.f;
    if (q < 2) {
        ucell  = u0 + q;
        cstate = c0[(size_t)lane * Hh + ucell];
        bi = bias[ucell];
        bf = bias[ucell + Hh];
        bg = bias[ucell + 2 * Hh];
        bo = bias[ucell + 3 * Hh];
    }

    __syncthreads();
    // ---- barrier phase 1 arrival ----
    if (tid == 0) __hip_atomic_fetch_add(&ctr[(bl & 7) * CTR_STRIDE], 1u,
                                         __ATOMIC_RELAXED, __HIP_MEMORY_SCOPE_AGENT);

    // ---- x-part prologue for t=0 (hidden under barrier settle) ----
    const float* xrow_base = x + (size_t)bb * Ss * CINc + 4 * sub;
    float4 xv[8];
    float  accx[SLOTS];
    {
        #pragma unroll
        for (int j = 0; j < 8; ++j) xv[j] = load4_glb(xrow_base + 32 * j);   // t=0
        wait_vm0();
        __builtin_amdgcn_sched_barrier(0);
        #pragma unroll
        for (int s = 0; s < SLOTS; ++s) accx[s] = 0.f;
        #pragma unroll
        for (int j = 0; j < 8; ++j) gfma(wqs4, 64 * j, xv[j], accx);
    }

    if (tid < NCTR) {
        while (__hip_atomic_load(&ctr[tid * CTR_STRIDE],
                                 __ATOMIC_RELAXED, __HIP_MEMORY_SCOPE_AGENT) < 32u)
            __builtin_amdgcn_s_sleep(2);
    }
    __atomic_signal_fence(__ATOMIC_SEQ_CST);
    __syncthreads();

    for (int t = 0; t < Ss; ++t) {
        const int cur = t & 1;
        const float* hcur = hbuf + (size_t)cur * Bb * Hh;
        float*       hnxt = hbuf + (size_t)(cur ^ 1) * Bb * Hh;

        // ---- issue all 16 h loads (LLC, coalesced per-instr: 8 full lines) ----
        const float* hrow = hcur + (size_t)bb * Hh + 4 * sub;
        float4 hv[16];
        #pragma unroll
        for (int j = 0; j < 16; ++j) hv[j] = load4_llc(hrow + 32 * j);

        float acc[SLOTS];
        #pragma unroll
        for (int s = 0; s < SLOTS; ++s) acc[s] = accx[s];

        wait_vm8();   // hv[0..7] landed (in-order retirement)
        #pragma unroll
        for (int j = 0; j < 8; ++j) gfma(wqs4, 512 + 64 * j, hv[j], acc);

        // ---- issue next step's x loads (cached); vmcnt = 8 h + 8 x ----
        {
            const int tn = (t + 1) & (Ss - 1);   // t=Ss-1 wraps (result unused)
            const float* xrow = xrow_base + (size_t)tn * CINc;
            #pragma unroll
            for (int j = 0; j < 8; ++j) xv[j] = load4_glb(xrow + 32 * j);
        }

        wait_vm8();   // drains to 8 outstanding -> all h done (x still in flight)
        #pragma unroll
        for (int j = 8; j < 16; ++j) gfma(wqs4, 512 + 64 * j, hv[j], acc);

        // ---- gate partial reduction via LDS ----
        #pragma unroll
        for (int s = 0; s < SLOTS; ++s) g_par[sub * 516 + s * 64 + bb] = acc[s];
        asm volatile("s_waitcnt lgkmcnt(0)" ::: "memory");
        __builtin_amdgcn_sched_barrier(0);
        __builtin_amdgcn_s_barrier();
        asm volatile("" ::: "memory");

        if (q < 2) {   // waves 0,1: cell update for units u0+q, batch = lane
            float s0 = 0.f, s1 = 0.f, s2 = 0.f, s3 = 0.f;
            #pragma unroll
            for (int w = 0; w < 8; ++w) {
                s0 += g_par[w * 516 + (0 + q) * 64 + lane];   // gate i
                s1 += g_par[w * 516 + (2 + q) * 64 + lane];   // gate f
                s2 += g_par[w * 516 + (4 + q) * 64 + lane];   // gate g
                s3 += g_par[w * 516 + (6 + q) * 64 + lane];   // gate o
            }
            float iv = sigf(s0 + bi);
            float fv = sigf(s1 + bf);
            float gv = tanhf(s2 + bg);
            float ov = sigf(s3 + bo);
            cstate = fv * cstate + iv * gv;
            float hv_ = ov * tanhf(cstate);
            store_llc(&hnxt[(size_t)lane * Hh + ucell], hv_);   // coherent publish
            out[((size_t)lane * Ss + t) * Hh + ucell] = hv_;
            if (t == Ss - 1) {
                out[(size_t)Bb * Ss * Hh + (size_t)lane * Hh + ucell] = hv_;
                out[(size_t)Bb * Ss * Hh + (size_t)Bb * Hh + (size_t)lane * Hh + ucell] = cstate;
            }
        }
        wait_vm0();        // drain h store (critical) + out stores + x prefetch
        __builtin_amdgcn_s_barrier();
        asm volatile("" ::: "memory");

        // ---- grid barrier arrival, phase t+2 ----
        if (tid == 0) __hip_atomic_fetch_add(&ctr[(bl & 7) * CTR_STRIDE], 1u,
                                             __ATOMIC_RELAXED, __HIP_MEMORY_SCOPE_AGENT);

        // ---- x-part GEMM for step t+1, hidden under barrier settle ----
        #pragma unroll
        for (int s = 0; s < SLOTS; ++s) accx[s] = 0.f;
        #pragma unroll
        for (int j = 0; j < 8; ++j) gfma(wqs4, 64 * j, xv[j], accx);

        const unsigned target = 32u * (unsigned)(t + 2);
        if (tid < NCTR) {
            while (__hip_atomic_load(&ctr[tid * CTR_STRIDE],
                                     __ATOMIC_RELAXED, __HIP_MEMORY_SCOPE_AGENT) < target)
                __builtin_amdgcn_s_sleep(2);
        }
        __atomic_signal_fence(__ATOMIC_SEQ_CST);
        __builtin_amdgcn_s_barrier();
        asm volatile("" ::: "memory");
    }
}

extern "C" void kernel_launch(void* const* d_in, const int* in_sizes, int n_in,
                              void* d_out, int out_size, void* d_ws, size_t ws_size,
                              hipStream_t stream) {
    const float* x    = (const float*)d_in[0];
    const float* W    = (const float*)d_in[1];
    const float* bias = (const float*)d_in[2];
    const float* h0   = (const float*)d_in[3];
    const float* c0   = (const float*)d_in[4];
    float* out = (float*)d_out;

    float*    wt   = (float*)d_ws;
    float*    hbuf = wt + WT_FLOATS;
    unsigned* ctr  = (unsigned*)(hbuf + HBUF_FLOATS);

    hipMemsetAsync(ctr, 0, NCTR * CTR_STRIDE * sizeof(unsigned), stream);
    extract_weights<<<256, 256, 0, stream>>>(W, wt);

    void* args[] = { (void*)&x, (void*)&bias, (void*)&h0, (void*)&c0,
                     (void*)&wt, (void*)&hbuf, (void*)&ctr, (void*)&out };
    hipLaunchCooperativeKernel((const void*)lstm_coop, dim3(NBLK), dim3(NTHR),
                               args, 0, stream);
}